// Round 3
// baseline (270.598 us; speedup 1.0000x reference)
//
#include <hip/hip_runtime.h>
#include <math.h>

// IntGELU: out = (x/sf) * floor( floor(2^31 / min(e + e_m, 2^31)) * e / 2^24 ) * sf/128
// where e = int_exp_shift(x/sf - rowmax), e_m = int_exp_shift(-rowmax), rows of 3072.

#define ROWLEN   3072
#define NTHREADS 256
#define PERTHREAD 12   // 3 x float4 per thread

typedef float f32x4 __attribute__((ext_vector_type(4)));  // clang-native vec for nt store

__device__ __forceinline__ float int_exp_shift(float xi, float x0) {
    #pragma clang fp contract(off)
    // t = xi + floor(xi/2) - floor(xi/16)   (left-to-right, /2 and /16 exact as mults)
    float t = (xi + floorf(xi * 0.5f)) - floorf(xi * 0.0625f);
    t = fmaxf(t, 23.0f * x0);              // clamp to N_SHIFT * x0
    float q = floorf(t / x0);              // genuine IEEE divide (x0 not a power of 2)
    float r = t - x0 * q;                  // contract(off): mul rounds, then sub
    float e = r * 0.5f - x0;
    int sh = 23 - (int)q;                  // q integer-valued in [0,23]
    e = floorf(ldexpf(e, sh));             // e * 2^(23-q), exact scaling
    return fmaxf(e, 0.0f);
}

__global__ __launch_bounds__(NTHREADS)
void intgelu_kernel(const float* __restrict__ x, const float* __restrict__ sfp,
                    float* __restrict__ out, int nrows, long long scalar_idx) {
    #pragma clang fp contract(off)
    const float sf  = sfp[0];
    const int   row = blockIdx.x;
    const int   tid = threadIdx.x;
    const float* xr   = x   + (size_t)row * ROWLEN;
    float*       outr = out + (size_t)row * ROWLEN;

    // ---- pass 1: load + divide + local max (stays in registers) ----
    float pre[PERTHREAD];
    float lmax = -INFINITY;
    #pragma unroll
    for (int c = 0; c < 3; ++c) {
        float4 v = reinterpret_cast<const float4*>(xr)[c * NTHREADS + tid];
        float p0 = v.x / sf, p1 = v.y / sf, p2 = v.z / sf, p3 = v.w / sf;
        pre[c*4+0] = p0; pre[c*4+1] = p1; pre[c*4+2] = p2; pre[c*4+3] = p3;
        lmax = fmaxf(lmax, fmaxf(fmaxf(p0, p1), fmaxf(p2, p3)));
    }

    // ---- block max reduce: 64-lane wave shuffle, then 4 waves via LDS ----
    #pragma unroll
    for (int off = 32; off > 0; off >>= 1)
        lmax = fmaxf(lmax, __shfl_down(lmax, off, 64));
    __shared__ float smax[NTHREADS / 64];
    if ((tid & 63) == 0) smax[tid >> 6] = lmax;
    __syncthreads();
    const float m = fmaxf(fmaxf(smax[0], smax[1]), fmaxf(smax[2], smax[3]));

    // ---- per-row constants (computed redundantly per thread, ~15 flops) ----
    const float sf_sig = sf * 1.702f;
    const float x0     = floorf(-1.0f / sf_sig);
    const float em     = int_exp_shift(0.0f - m, x0);   // exp_int of (-rowmax)
    const float out_sf = sf * 0.0078125f;               // sf / 2^7

    // ---- pass 2: elementwise finish + coalesced nontemporal float4 stores ----
    #pragma unroll
    for (int c = 0; c < 3; ++c) {
        f32x4 o;
        #pragma unroll
        for (int j = 0; j < 4; ++j) {
            float p  = pre[c*4+j];
            float e  = int_exp_shift(p - m, x0);
            float s  = fminf(e + em, 2147483647.0f);        // == 2^31 in f32
            float f  = floorf(2147483647.0f / s);           // genuine IEEE divide
            float sg = floorf((e * f) * 5.9604644775390625e-8f); // / 2^24 (exact mult)
            o[j] = (p * sg) * out_sf;
        }
        __builtin_nontemporal_store(o, &reinterpret_cast<f32x4*>(outr)[c * NTHREADS + tid]);
    }

    // ---- second tuple output: the scalar out_sf (last element of flat d_out) ----
    if (row == 0 && tid == 0) out[scalar_idx] = out_sf;
}

extern "C" void kernel_launch(void* const* d_in, const int* in_sizes, int n_in,
                              void* d_out, int out_size, void* d_ws, size_t ws_size,
                              hipStream_t stream) {
    const float* x   = (const float*)d_in[0];
    const float* sfp = (const float*)d_in[1];
    float*       out = (float*)d_out;
    const int nrows  = in_sizes[0] / ROWLEN;            // 64*197 = 12608
    const long long scalar_idx = (long long)out_size - 1;
    intgelu_kernel<<<nrows, NTHREADS, 0, stream>>>(x, sfp, out, nrows, scalar_idx);
}

// Round 4
// 269.585 us; speedup vs baseline: 1.0038x; 1.0038x over previous
//
#include <hip/hip_runtime.h>
#include <math.h>

// IntGELU: out = (x/sf) * floor( floor(2^31 / min(e + e_m, 2^31)) * e / 2^24 ) * sf/128
// e = int_exp_shift(x/sf - rowmax), e_m = int_exp_shift(-rowmax), rows of 3072.
//
// Numerics notes (bit-exactness vs XLA reference):
//  - rowmax taken over RAW x, divided once: RN-div is monotone, so
//    max_i RN(x_i/sf) == RN(max_i x_i / sf). Exact.
//  - power-of-two divides are exact multiplies; ldexpf is exact.
//  - contract(off): r = t - x0*q must round the mul separately (no FMA fuse).
//  - t/x0 replaced by t*(1/x0): <=1.5ulp; q-boundary is continuous in e, so
//    rare floor flips cost <=1 sigmoid unit (~0.04 in output). em keeps IEEE.
//  - x/sf and 2^31/s stay genuine IEEE divides (f-flips amplify by e/2^24).

#define ROWLEN   3072
#define NTHREADS 256

typedef float f32x4 __attribute__((ext_vector_type(4)));

__device__ __forceinline__ float int_exp_exact(float xi, float x0) {
    #pragma clang fp contract(off)
    float t = (xi + floorf(xi * 0.5f)) - floorf(xi * 0.0625f);
    t = fmaxf(t, 23.0f * x0);
    float q = floorf(t / x0);              // IEEE divide (used once per thread)
    float r = t - x0 * q;
    float e = r * 0.5f - x0;
    e = floorf(ldexpf(e, 23 - (int)q));
    return fmaxf(e, 0.0f);
}

__device__ __forceinline__ float int_exp_fast(float xi, float x0, float inv_x0,
                                              float c23x0) {
    #pragma clang fp contract(off)
    float t = (xi + floorf(xi * 0.5f)) - floorf(xi * 0.0625f);
    t = fmaxf(t, c23x0);
    float q = floorf(t * inv_x0);          // mult by precomputed 1/x0
    float r = t - x0 * q;                  // contract off: mul rounds, then sub
    float e = r * 0.5f - x0;
    e = floorf(ldexpf(e, 23 - (int)q));
    return fmaxf(e, 0.0f);
}

__global__ __launch_bounds__(NTHREADS)
void intgelu_kernel(const float* __restrict__ x, const float* __restrict__ sfp,
                    float* __restrict__ out, long long scalar_idx) {
    #pragma clang fp contract(off)
    const int   row = blockIdx.x;
    const int   tid = threadIdx.x;
    const float* xr   = x   + (size_t)row * ROWLEN;
    float*       outr = out + (size_t)row * ROWLEN;

    // ---- pass 1: loads + RAW max only (no divides before the barrier) ----
    float xv[12];
    float lmax = -INFINITY;
    #pragma unroll
    for (int c = 0; c < 3; ++c) {
        float4 v = reinterpret_cast<const float4*>(xr)[c * NTHREADS + tid];
        xv[c*4+0] = v.x; xv[c*4+1] = v.y; xv[c*4+2] = v.z; xv[c*4+3] = v.w;
        lmax = fmaxf(lmax, fmaxf(fmaxf(v.x, v.y), fmaxf(v.z, v.w)));
    }

    #pragma unroll
    for (int off = 32; off > 0; off >>= 1)
        lmax = fmaxf(lmax, __shfl_xor(lmax, off, 64));
    __shared__ float smax[NTHREADS / 64];
    if ((tid & 63) == 0) smax[tid >> 6] = lmax;
    __syncthreads();
    const float mraw = fmaxf(fmaxf(smax[0], smax[1]), fmaxf(smax[2], smax[3]));

    // ---- per-row constants ----
    const float sf     = sfp[0];
    const float m      = mraw / sf;                 // == max_i(x_i/sf), monotone RN
    const float x0     = floorf(-1.0f / (sf * 1.702f));
    const float inv_x0 = 1.0f / x0;                 // IEEE, once
    const float c23x0  = 23.0f * x0;
    const float em     = int_exp_exact(0.0f - m, x0);
    const float out_sf = sf * 0.0078125f;           // sf / 2^7

    // ---- pass 2: divide + elementwise finish + nt float4 stores ----
    #pragma unroll
    for (int c = 0; c < 3; ++c) {
        f32x4 o;
        #pragma unroll
        for (int j = 0; j < 4; ++j) {
            float p  = xv[c*4+j] / sf;                      // IEEE divide
            float e  = int_exp_fast(p - m, x0, inv_x0, c23x0);
            float s  = fminf(e + em, 2147483647.0f);        // == 2^31 in f32
            float f  = floorf(2147483647.0f / s);           // IEEE divide
            float sg = floorf((e * f) * 5.9604644775390625e-8f); // * 2^-24 exact
            o[j] = (p * sg) * out_sf;
        }
        __builtin_nontemporal_store(o, &reinterpret_cast<f32x4*>(outr)[c * NTHREADS + tid]);
    }

    // ---- second tuple output: the scalar out_sf ----
    if (row == 0 && tid == 0) out[scalar_idx] = out_sf;
}

extern "C" void kernel_launch(void* const* d_in, const int* in_sizes, int n_in,
                              void* d_out, int out_size, void* d_ws, size_t ws_size,
                              hipStream_t stream) {
    const float* x   = (const float*)d_in[0];
    const float* sfp = (const float*)d_in[1];
    float*       out = (float*)d_out;
    const int nrows  = in_sizes[0] / ROWLEN;            // 64*197 = 12608
    const long long scalar_idx = (long long)out_size - 1;
    intgelu_kernel<<<nrows, NTHREADS, 0, stream>>>(x, sfp, out, scalar_idx);
}